// Round 10
// baseline (119.938 us; speedup 1.0000x reference)
//
#include <hip/hip_runtime.h>
#include <cmath>

namespace {

typedef _Float16 half8_t __attribute__((ext_vector_type(8)));
typedef _Float16 half4_t __attribute__((ext_vector_type(4)));
typedef float    f32x4_t __attribute__((ext_vector_type(4)));

constexpr int R_ = 8, M1_ = 32, N1_ = 64, M2_ = 24, N2_ = 48;
constexpr int DIN = 768;          // M1*M2
constexpr int T_TOK = 8;          // tokens per workgroup -> grid 512 = 2 x 256 CUs
constexpr int NTHREADS = 512;     // 8 waves

// ---- d_ws f16 weights (element offsets), all *64 (2^6, exact), MFMA
// fragment-native (rows = operand rows, k contiguous, 16B-aligned).
constexpr int W1_OFF = 0;         // [r][j=48][k=40]  = B1[r][k][j]; k>=24 -> 0
constexpr int W2_OFF = 30720;     // [n1=64][r*32+i]  = A1[r][n1][i]
constexpr int W3_OFF = 47104;     // [r*32+m1][n1=64] = A2 flat
constexpr int W4_OFF = 63488;     // [m2=32][r*48+n2] = B2[r][n2][m2]; m2>=24 -> 0
constexpr int W_TOTAL = 75776;    // 151552 B in d_ws

// ---- LDS (f16 element offsets), 80384 B -> 2 blocks/CU, grid fully resident.
// Phase A is BARRIER-FREE: wave w owns token w entirely. Slab w (3456 f16 =
// 6912 B) hosts, in lifetime order (all intra-wave, DS-ordered):
//   XP_w [32][40] at +0 (1280), T1_w [48][40] at +1280 (1920), then the
//   epilogue's HG rows w*48..w*48+47 overwrite the slab ([48][72] = 3456).
// Phase B (after the single barrier): HG slabs read cross-wave; ZP at 27648;
// per-token stage-4 partials P[2][768] f32 reuse that token's dead HG slab.
constexpr int SLAB  = 3456;       // f16 per token slab (= 48*72)
constexpr int T1_L  = 1280;       // T1 offset inside slab
constexpr int HG_H  = 0;          // HG rows s=(t*48+n2), stride 72
constexpr int ZP_H  = 27648;      // [32][392]
constexpr int LDS_BYTES = (27648 + 12544) * 2;   // 80384

__global__ void prep_weights(const float* __restrict__ A1, const float* __restrict__ B1,
                             const float* __restrict__ A2, const float* __restrict__ B2,
                             _Float16* __restrict__ W)
{
    const int idx = blockIdx.x * 256 + threadIdx.x;
    if (idx >= W_TOTAL) return;
    float v;
    if (idx < W2_OFF) {                       // W1[r][j][k] = B1[r][k][j]
        int k = idx % 40, j = (idx / 40) % 48, r = idx / 1920;
        v = (k < 24) ? B1[(r * 24 + k) * 48 + j] : 0.0f;
    } else if (idx < W3_OFF) {                // W2[n1][r*32+i] = A1[r][n1][i]
        int t = idx - W2_OFF;
        int rk = t & 255, n1 = t >> 8;
        v = A1[((rk >> 5) * 64 + n1) * 32 + (rk & 31)];
    } else if (idx < W4_OFF) {                // W3 = A2 flat
        v = A2[idx - W3_OFF];
    } else {                                  // W4[m2][r*48+n2] = B2[r][n2][m2]
        int t = idx - W4_OFF;
        int k = t % 384, m2 = t / 384;
        v = (m2 < 24) ? B2[k * 24 + m2] : 0.0f;
    }
    W[idx] = (_Float16)(v * 64.0f);
}

__global__ __launch_bounds__(NTHREADS, 4)
void kn_mfma(const float* __restrict__ x,
             const float* __restrict__ b1,
             const float* __restrict__ b2,
             const int* __restrict__ p_inv,
             const int* __restrict__ q,
             const _Float16* __restrict__ W,
             float* __restrict__ out)
{
    extern __shared__ char smem[];
    _Float16* ldsH = (_Float16*)smem;
    float*    ldsF = (float*)smem;

    const int tid  = threadIdx.x;
    const int lane = tid & 63;
    const int w    = __builtin_amdgcn_readfirstlane(tid >> 6);  // uniform wave id
    const int quad = lane >> 4;
    const int l16  = lane & 15;

    const long tokBase = (long)blockIdx.x * T_TOK;
    // p_inv/q may be int64 or int32; a permutation can't have two zeros.
    const bool idx64 = (p_inv[1] == 0 && p_inv[3] == 0);

    _Float16* slab = ldsH + w * SLAB;       // wave-private token slab

    // ---------------- fill XP_w[i][m2] = f16(x[tok w][p_inv[i*24+m2]]) -------
    // Wave-private: intra-wave DS ordering only, no barrier anywhere in phase A.
    {
        const float* xrow = x + (size_t)(tokBase + w) * DIN;
        #pragma unroll
        for (int c = 0; c < 12; ++c) {
            const int kIdx = c * 64 + lane;
            const int pidx = idx64 ? p_inv[2 * kIdx] : p_inv[kIdx];
            const int i = kIdx / 24, m2 = kIdx - i * 24;
            slab[i * 40 + m2] = (_Float16)xrow[pidx];
        }
        // zero k-pad cols [24,40): lane -> (row, 8 cols)
        const int r0 = lane >> 1, c0 = 24 + (lane & 1) * 8;
        *(half8_t*)&slab[r0 * 40 + c0] = half8_t{0, 0, 0, 0, 0, 0, 0, 0};
    }

    const f32x4_t zero4 = {0.f, 0.f, 0.f, 0.f};

    // stage-1 A fragments (r-invariant): token w's 32 i-rows.
    const half8_t xp0 = *(const half8_t*)&slab[l16 * 40 + quad * 8];
    const half8_t xp1 = *(const half8_t*)&slab[(16 + l16) * 40 + quad * 8];

    // h accumulators: wave w holds ALL of token w: h[n1=64][n2=48] * 2^12,
    // tile u = a*3+c (a: n1-tile 0..3, c: n2-tile 0..2).
    f32x4_t hacc[12];
    #pragma unroll
    for (int u = 0; u < 12; ++u) hacc[u] = zero4;

    _Float16* t1 = slab + T1_L;

    // ---------------- phase A: BARRIER-FREE, wave-private ---------------------
    #pragma unroll
    for (int r = 0; r < R_; ++r) {
        // stage 1: T1_w[j][i] = XP_w * (B1_r*64)   (3 j-tiles, K=32 covers m2)
        #pragma unroll
        for (int ct = 0; ct < 3; ++ct) {
            const half8_t bf = *(const half8_t*)&W[W1_OFF + (r * 48 + ct * 16 + l16) * 40 + quad * 8];
            const f32x4_t c0 = __builtin_amdgcn_mfma_f32_16x16x32_f16(xp0, bf, zero4, 0, 0, 0);
            const f32x4_t c1 = __builtin_amdgcn_mfma_f32_16x16x32_f16(xp1, bf, zero4, 0, 0, 0);
            half4_t p;
            p[0] = (_Float16)c0[0]; p[1] = (_Float16)c0[1];
            p[2] = (_Float16)c0[2]; p[3] = (_Float16)c0[3];
            *(half4_t*)&t1[(ct * 16 + l16) * 40 + quad * 4] = p;          // i 0..15
            p[0] = (_Float16)c1[0]; p[1] = (_Float16)c1[1];
            p[2] = (_Float16)c1[2]; p[3] = (_Float16)c1[3];
            *(half4_t*)&t1[(ct * 16 + l16) * 40 + 16 + quad * 4] = p;     // i 16..31
        }
        // stage 2: hacc[a][c] += (A1_r*64)[n1-tile a] * T1_w[n2-tile c] (K=i=32)
        #pragma unroll
        for (int a = 0; a < 4; ++a) {
            const half8_t af = *(const half8_t*)&W[W2_OFF + (a * 16 + l16) * 256 + r * 32 + quad * 8];
            #pragma unroll
            for (int c = 0; c < 3; ++c) {
                const half8_t bf = *(const half8_t*)&t1[(c * 16 + l16) * 40 + quad * 8];
                hacc[a * 3 + c] = __builtin_amdgcn_mfma_f32_16x16x32_f16(af, bf, hacc[a * 3 + c], 0, 0, 0);
            }
        }
    }

    // ---------------- epilogue: h = hacc/4096 + b1; HgT = gelu(h)*4096 -------
    // Overwrites XP/T1 in the private slab (intra-wave DS order; no barrier).
    {
        const float inv4096 = 1.0f / 4096.0f;
        #pragma unroll
        for (int a = 0; a < 4; ++a)
            #pragma unroll
            for (int c = 0; c < 3; ++c) {
                const int n2  = c * 16 + l16;
                const int n1b = a * 16 + quad * 4;
                half4_t p;
                #pragma unroll
                for (int rg = 0; rg < 4; ++rg) {
                    const float hv = hacc[a * 3 + c][rg] * inv4096 + b1[(n1b + rg) * 48 + n2];
                    float g;
                    if (__builtin_expect(fabsf(hv) < 0.04f, 1)) {
                        g = fmaf(0.3989422804f * hv, hv, 0.5f * hv);  // |err| = O(h^4)
                    } else {
                        g = 0.5f * hv * (1.0f + erff(hv * 0.70710678118654752f));
                    }
                    p[rg] = (_Float16)(g * 4096.0f);
                }
                // HgT[(t=w)*48 + n2][n1] row inside slab w
                *(half4_t*)&ldsH[HG_H + (w * 48 + n2) * 72 + n1b] = p;
            }
    }

    // ---------------- phase-B hoists (token-invariant, register-resident) ----
    const int kh  = w >> 2;        // stage-4 k-half (r 0..3 | 4..7)
    const int rt4 = (w >> 1) & 1;  // stage-4 m1 tile
    const int ct4 = w & 1;         // stage-4 m2 tile
    const float sc = 1.0f / 16777216.0f;   // 2^-24

    // stage-3 B-operand (A2 rows = m1); wave w owns r=w
    half8_t w3f[2][2];
    #pragma unroll
    for (int e = 0; e < 2; ++e)
        #pragma unroll
        for (int kk = 0; kk < 2; ++kk)
            w3f[e][kk] = *(const half8_t*)&W[W3_OFF + (w * 32 + e * 16 + l16) * 64 + kk * 32 + quad * 8];

    // stage-4 A-operand (B2 rows = m2), K-half kh
    half8_t w4f[6];
    #pragma unroll
    for (int kk = 0; kk < 6; ++kk)
        w4f[kk] = *(const half8_t*)&W[W4_OFF + (ct4 * 16 + l16) * 384 + kh * 192 + kk * 32 + quad * 8];

    // final-store q/b2 (token-invariant)
    const int  qa = idx64 ? q[2 * tid] : q[tid];
    const float ba = b2[qa];
    const bool has2 = tid < DIN - 512;
    int qb = 0; float bb = 0.f;
    if (has2) {
        qb = idx64 ? q[2 * (512 + tid)] : q[512 + tid];
        bb = b2[qb];
    }
    __syncthreads();   // the ONLY barrier between phase A and phase B

    // ---------------- phase B per token ---------------------------------------
    // stage 3 (swapped): D[(t,n2)][m1] = Hg' x (A2*64): lane holds 4 consecutive
    // n2 at fixed m1 -> one b64 scatter per tile into Z'[m1][r*48+n2].
    // stage 4 (swapped): D[m2][m1] = (B2'*64) x Z': lane holds 4 consecutive m2
    // at fixed m1 -> one masked b128 write into P[kh][m1*24+m2].
    for (int tt = 0; tt < T_TOK; ++tt) {
        f32x4_t zc[6];
        #pragma unroll
        for (int u = 0; u < 6; ++u) zc[u] = zero4;
        #pragma unroll
        for (int ct = 0; ct < 3; ++ct)
            #pragma unroll
            for (int kk = 0; kk < 2; ++kk) {
                const half8_t af = *(const half8_t*)&ldsH[HG_H + (tt * 48 + ct * 16 + l16) * 72 + kk * 32 + quad * 8];
                #pragma unroll
                for (int e = 0; e < 2; ++e) {
                    const int u = ct * 2 + e;
                    zc[u] = __builtin_amdgcn_mfma_f32_16x16x32_f16(af, w3f[e][kk], zc[u], 0, 0, 0);
                }
            }
        // scatter: Z'[m1 = e*16+l16][w*48 + ct*16 + quad*4 + rg], b64 each
        #pragma unroll
        for (int ct = 0; ct < 3; ++ct)
            #pragma unroll
            for (int e = 0; e < 2; ++e) {
                const int u = ct * 2 + e;
                half4_t p;
                p[0] = (_Float16)zc[u][0]; p[1] = (_Float16)zc[u][1];
                p[2] = (_Float16)zc[u][2]; p[3] = (_Float16)zc[u][3];
                *(half4_t*)&ldsH[ZP_H + (e * 16 + l16) * 392 + w * 48 + ct * 16 + quad * 4] = p;
            }
        __syncthreads();   // scatter visible; all stage-3 reads of HG slab tt done

        // stage 4: oc = (B2'*64) x Z'  (K-half = 192 per wave)
        f32x4_t oc = zero4;
        #pragma unroll
        for (int kk = 0; kk < 6; ++kk) {
            const half8_t zf = *(const half8_t*)&ldsH[ZP_H + (rt4 * 16 + l16) * 392 + kh * 192 + kk * 32 + quad * 8];
            oc = __builtin_amdgcn_mfma_f32_16x16x32_f16(w4f[kk], zf, oc, 0, 0, 0);
        }
        // P[kh][m1*24+m2], contiguous 4 m2 -> b128; slab tt (1728 f32)
        {
            const int m2b = ct4 * 16 + quad * 4;
            if (m2b < M2_) {
                *(f32x4_t*)&ldsF[1728 * tt + kh * 768 + (rt4 * 16 + l16) * 24 + m2b] = oc;
            }
        }
        __syncthreads();   // partials visible; ZP free for next tt

        // per-token final: sum halves, *2^-24, +b2, q-gather, coalesced store
        {
            const float* Pb = ldsF + 1728 * tt;
            float* orow = out + (size_t)(tokBase + tt) * DIN;
            orow[tid] = (Pb[qa] + Pb[768 + qa]) * sc + ba;
            if (has2)
                orow[512 + tid] = (Pb[qb] + Pb[768 + qb]) * sc + bb;
        }
        // next stage-3 touches HG slabs > tt and ZP only; safe without barrier
    }
}

} // namespace

extern "C" void kernel_launch(void* const* d_in, const int* in_sizes, int n_in,
                              void* d_out, int out_size, void* d_ws, size_t ws_size,
                              hipStream_t stream) {
    const float* x   = (const float*)d_in[0];
    const float* A1  = (const float*)d_in[1];
    const float* B1  = (const float*)d_in[2];
    const float* A2  = (const float*)d_in[3];
    const float* B2  = (const float*)d_in[4];
    const float* b1  = (const float*)d_in[5];
    const float* b2  = (const float*)d_in[6];
    const int*   piv = (const int*)d_in[7];
    const int*   q   = (const int*)d_in[8];
    float* out = (float*)d_out;
    _Float16* Wws = (_Float16*)d_ws;

    const int tokens = in_sizes[0] / DIN;          // 4096
    const int grid   = tokens / T_TOK;             // 512 = 2 per CU, 1 generation

    prep_weights<<<(W_TOTAL + 255) / 256, 256, 0, stream>>>(A1, B1, A2, B2, Wws);

    (void)hipFuncSetAttribute((const void*)kn_mfma,
                              hipFuncAttributeMaxDynamicSharedMemorySize,
                              LDS_BYTES);
    kn_mfma<<<grid, NTHREADS, LDS_BYTES, stream>>>(x, b1, b2, piv, q, Wws, out);
}